// Round 7
// baseline (546.098 us; speedup 1.0000x reference)
//
#include <hip/hip_runtime.h>

typedef unsigned short u16;
typedef __attribute__((ext_vector_type(8))) short short8;   // 8 bf16 (4 VGPRs) MFMA frag
typedef __attribute__((ext_vector_type(4))) float f32x4;
typedef __attribute__((ext_vector_type(4))) unsigned short u16x4;
typedef __attribute__((ext_vector_type(8))) unsigned short u16x8;

#define BTOK 16384      // B*S = 4*4096
#define PROJ_N 2576
#define PROJ_PAD 2688   // 21 * 128 (divisible by BN=128)
#define DK 1024         // D_MODEL = D_INNER
#define NCH 256         // B * nChunks = 4*64
#define NH 16
#define HD 64
#define NS 16           // D_STATE

__device__ __forceinline__ float b2f(u16 b) {
    union { unsigned int u; float f; } v; v.u = ((unsigned int)b) << 16; return v.f;
}
__device__ __forceinline__ u16 f2b(float f) {
    union { float f; unsigned int u; } v; v.f = f;
    unsigned int r = v.u + 0x7fffu + ((v.u >> 16) & 1u);
    return (u16)(r >> 16);
}

// Inline-asm global->LDS staging (16B/lane), invisible to the waitcnt pass.
// LDS dest = M0 (wave-uniform byte offset via readfirstlane) + lane*16.
__device__ __forceinline__ void stage_asm(const u16* g, const u16* l) {
    unsigned loff = (unsigned)(size_t)(const __attribute__((address_space(3))) u16*)l;
    unsigned su = __builtin_amdgcn_readfirstlane(loff);
    asm volatile("s_mov_b32 m0, %1\n\t"
                 "global_load_lds_dwordx4 %0, off"
                 :: "v"(g), "s"(su));
}

// Inline-asm ds_read_b128, invisible. Ordering vs MFMA via counted lgkmcnt +
// sched_barrier(0) (rule #18). DS ops complete in-order per wave, and no other
// lgkm-counted ops (SMEM/flat) occur in the loop, so counted waits are exact.
template <int IMM>
__device__ __forceinline__ short8 dsr128(unsigned a) {
    short8 d;
    asm volatile("ds_read_b128 %0, %1 offset:%2" : "=v"(d) : "v"(a), "i"(IMM));
    return d;
}

#define LGKM(n) do { asm volatile("s_waitcnt lgkmcnt(" #n ")"); __builtin_amdgcn_sched_barrier(0); } while (0)
#define MFMA_B16 __builtin_amdgcn_mfma_f32_16x16x32_bf16
#define SB0() __builtin_amdgcn_sched_barrier(0)

// ---------------- casts ----------------
__global__ __launch_bounds__(256) void cast_bf16(const float* __restrict__ s,
                                                 u16* __restrict__ d, int n4) {
    int t = blockIdx.x * 256 + threadIdx.x;
    if (t < n4) {
        float4 v = ((const float4*)s)[t];
        u16x4 o; o.x = f2b(v.x); o.y = f2b(v.y); o.z = f2b(v.z); o.w = f2b(v.w);
        ((u16x4*)d)[t] = o;
    }
}

__global__ __launch_bounds__(256) void cast_pad_win(const float* __restrict__ s,
                                                    u16* __restrict__ d) {
    int t = blockIdx.x * 256 + threadIdx.x;
    int i4 = t * 4;
    float4 v = make_float4(0.f, 0.f, 0.f, 0.f);
    if (i4 < PROJ_N * DK) v = ((const float4*)s)[t];
    u16x4 o; o.x = f2b(v.x); o.y = f2b(v.y); o.z = f2b(v.z); o.w = f2b(v.w);
    ((u16x4*)d)[t] = o;
}

// ---------------- flatmm GEMM: C[M,N] = A[M,K]*B[N,K]^T ----------------
// 256x128 tile, 4 waves (2M x 2N), wave tile 128x64, BK=64.
// A: per-lane C++ short8 loads direct from L1/L2 in MFMA fragment layout
//    (row = mw*128+f*16+m_l, k = quad*8 + ks*32 -- same mapping as the verified
//    LDS path). Compiler-visible => compiler inserts its own counted vmcnt for
//    fragment uses; my invisible DMA stages only make those waits stronger
//    (vmcnt drains oldest-first), never weaker.
// B: LDS 2x16KB double-buffer, DMA-staged, chunk-XOR swizzle (0 conflicts);
//    proven R3-R5 ledger: stage -> vmcnt(0) -> barrier per K-tile.
// => LDS carries only B (1/3 of prior traffic); A uses the vector-mem port;
//    32KB LDS + 4 waves => TWO blocks/CU co-resident (decoupled barriers).
// lgkm ledger per wave: boundary issues bfX x4; loop issues bfY x4 -> LGKM(4)
// completes bfX; LGKM(0) completes bfY. (A-loads are vm, not lgkm.)
#define MT 64   // M/256 for both GEMMs (M = 16384)

template <int OUT_BF16>
__global__ __launch_bounds__(256, 2) void gemmf(const u16* __restrict__ A,
                                                const u16* __restrict__ B,
                                                float* __restrict__ Cf,
                                                u16* __restrict__ Cb,
                                                int K, int ldc) {
    __shared__ u16 Bs[2 * 128 * 64];     // 32 KiB
    const int tid = threadIdx.x;
    const int wave = tid >> 6, lane = tid & 63;
    const int mw = wave >> 1, nw = wave & 1;
    const int m_l = lane & 15, quad = lane >> 4;

    // XCD-chunked 2D swizzle (gridDim.x % 64 == 0): XCD=b&7 owns 8 bm panels
    // (8 x 512KB = 4MB = its L2) and sweeps bn slowly.
    const int b = blockIdx.x;
    const int bm = (b & 7) * 8 + ((b >> 3) & 7);
    const int bn = b >> 6;

    const u16* Ab = A + (long)bm * 256 * K;
    const u16* Bb = B + (long)bn * 128 * K;

    // per-lane A fragment base: row = mw*128 + f*16 + m_l, k = quad*8 (+32 ks1)
    const u16* ap0 = Ab + (long)(mw * 128 + m_l) * K + quad * 8;
    const int fstride = 16 * K;

    // B LDS read bases; chunk slot = (ks*4+quad) ^ (row&7), row&7 == m_l&7
    const unsigned lds0 = (unsigned)(size_t)(const __attribute__((address_space(3))) u16*)Bs;
    const int sw = m_l & 7;
    const unsigned b0b = lds0 + (nw * 64 + m_l) * 128 + (quad ^ sw) * 16;
    const unsigned b1b = lds0 + (nw * 64 + m_l) * 128 + ((4 + quad) ^ sw) * 16;

    // staging thread-constants (pre-swizzled global src, linear LDS dest)
    const int srow = tid >> 3;               // 0..31
    const int schk = (tid & 7) ^ (srow & 7);

    f32x4 acc[8][4];
#pragma unroll
    for (int f = 0; f < 8; ++f)
#pragma unroll
        for (int n = 0; n < 4; ++n) acc[f][n] = (f32x4){0.f, 0.f, 0.f, 0.f};

    const int NT = K >> 6;

    auto stageB = [&](unsigned bufU16, int q, int k0) {
        stage_asm(Bb + (long)(q * 32 + srow) * K + k0 + schk * 8,
                  Bs + bufU16 + q * 2048 + wave * 512);
    };

    // prologue: tile0 B into buf0; then first bfX/afX
    stageB(0, 0, 0); stageB(0, 1, 0); stageB(0, 2, 0); stageB(0, 3, 0);
    asm volatile("s_waitcnt vmcnt(0)");
    __builtin_amdgcn_s_barrier();

    short8 afX[8], afY[8], bfX[4], bfY[4];
    bfX[0] = dsr128<0>(b0b);    bfX[1] = dsr128<2048>(b0b);
    bfX[2] = dsr128<4096>(b0b); bfX[3] = dsr128<6144>(b0b);
#pragma unroll
    for (int f = 0; f < 8; ++f) afX[f] = *(const short8*)(ap0 + f * fstride);

    unsigned curB = 0;                       // byte offset of current B buffer
    for (int t = 0; t < NT; ++t) {
        const bool s1 = (t + 1 < NT);
        const int k0 = t << 6, k1 = (t + 1) << 6;

        // issue ks1 reads (ds for B, C++ vm for A) early
        bfY[0] = dsr128<0>(b1b + curB);    bfY[1] = dsr128<2048>(b1b + curB);
        bfY[2] = dsr128<4096>(b1b + curB); bfY[3] = dsr128<6144>(b1b + curB);
#pragma unroll
        for (int f = 0; f < 8; ++f) afY[f] = *(const short8*)(ap0 + f * fstride + k0 + 32);

        // stage B(t+1) into the other buffer (WAR-safe: its last reads completed
        // at LGKM(0) before the previous tile-boundary barrier)
        if (s1) {
            unsigned nx = (curB >> 1) ^ 8192u;   // u16 units
            stageB(nx, 0, k1); stageB(nx, 1, k1); stageB(nx, 2, k1); stageB(nx, 3, k1);
        }

        // ks0 MFMA: bfX done (lgkm 8 outstanding -> 4); afX waits by compiler
        LGKM(4);
        __builtin_amdgcn_s_setprio(1);
#pragma unroll
        for (int f = 0; f < 8; ++f)
#pragma unroll
            for (int n = 0; n < 4; ++n)
                acc[f][n] = MFMA_B16(afX[f], bfX[n], acc[f][n], 0, 0, 0);
        __builtin_amdgcn_s_setprio(0);
        SB0();

        // ks1 MFMA: bfY done; afY waits by compiler
        LGKM(0);
        __builtin_amdgcn_s_setprio(1);
#pragma unroll
        for (int f = 0; f < 8; ++f)
#pragma unroll
            for (int n = 0; n < 4; ++n)
                acc[f][n] = MFMA_B16(afY[f], bfY[n], acc[f][n], 0, 0, 0);
        __builtin_amdgcn_s_setprio(0);
        SB0();

        // tile boundary: stages landed; swap; issue next tile's ks0 reads
        if (s1) {
            asm volatile("s_waitcnt vmcnt(0)");
            __builtin_amdgcn_s_barrier();
            curB ^= 16384u;
            bfX[0] = dsr128<0>(b0b + curB);    bfX[1] = dsr128<2048>(b0b + curB);
            bfX[2] = dsr128<4096>(b0b + curB); bfX[3] = dsr128<6144>(b0b + curB);
#pragma unroll
            for (int f = 0; f < 8; ++f) afX[f] = *(const short8*)(ap0 + f * fstride + k1);
        }
    }

    // C/D layout: col=lane&15, row=quad*4+reg (m89/m91 verified)
#pragma unroll
    for (int f = 0; f < 8; ++f) {
        int row_base = bm * 256 + mw * 128 + f * 16 + quad * 4;
#pragma unroll
        for (int n = 0; n < 4; ++n) {
            int col = bn * 128 + nw * 64 + n * 16 + m_l;
#pragma unroll
            for (int r = 0; r < 4; ++r) {
                float v = acc[f][n][r];
                long off = (long)(row_base + r) * ldc + col;
                if (OUT_BF16) Cb[off] = f2b(v);
                else          Cf[off] = v;
            }
        }
    }
}

// ---------------- intra-chunk: dt fold + scores + y_intra/cstate via MFMA ----------------
__global__ __launch_bounds__(256) void ssm_intra(const u16* __restrict__ proj,
                                                 const float* __restrict__ dt_W,
                                                 const float* __restrict__ dt_b,
                                                 const float* __restrict__ A_log,
                                                 float* __restrict__ dAcs,
                                                 float* __restrict__ decay,
                                                 u16* __restrict__ y_acc,
                                                 float* __restrict__ cstate) {
    int bch = blockIdx.x;             // (b*64+c)*16 + h
    int bc = bch >> 4, h = bch & 15;
    long tok0 = (long)bc * 64;
    __shared__ float Cs[64][20], Bm[64][20];
    __shared__ u16 Sh[64][72], Sl[64][72];   // scores hi/lo, [i][j] (A-operand layout)
    __shared__ u16 Xt[64][72];               // X^T: [p][j]   (B-operand for y_intra)
    __shared__ u16 Wh[64][72], Wl[64][72];   // (w*X)^T hi/lo: [p][k] (B-operand for cstate)
    __shared__ u16 Bt[16][72];               // B^T: [n][k]   (A-operand for cstate)
    __shared__ float dts[64], dAs[64], wk[64];
    const int tid = threadIdx.x;
    const int wave = tid >> 6, lane = tid & 63;
    const int m_l = lane & 15, quad = lane >> 4;

    if (tid < 64) {
        long tok = tok0 + tid;
        u16x8 lo0 = *(const u16x8*)&proj[tok * PROJ_PAD + 2560];
        u16x8 lo1 = *(const u16x8*)&proj[tok * PROJ_PAD + 2568];
        float a = dt_b[h];
#pragma unroll
        for (int r = 0; r < 8; ++r) a += b2f(lo0[r]) * dt_W[h * 16 + r];
#pragma unroll
        for (int r = 0; r < 8; ++r) a += b2f(lo1[r]) * dt_W[h * 16 + 8 + r];
        float d = (a > 20.f) ? a : log1pf(__expf(a));
        float dA = -__expf(A_log[h]) * d;
        float cs = dA;
#pragma unroll
        for (int off = 1; off < 64; off <<= 1) {
            float o = __shfl_up(cs, off, 64);
            if (tid >= off) cs += o;
        }
        float cs63 = __shfl(cs, 63, 64);
        dts[tid] = d;
        dAs[tid] = cs;
        wk[tid] = d * __expf(cs63 - cs);
        dAcs[tok * 16 + h] = cs;
        if (tid == 63) decay[bc * 16 + h] = __expf(cs);
    }
#pragma unroll
    for (int it = 0; it < 4; ++it) {
        int li = it * 256 + tid;
        int i = li >> 4, n = li & 15;
        u16 cb = proj[(tok0 + i) * PROJ_PAD + 2304 + h * 16 + n];
        u16 bb = proj[(tok0 + i) * PROJ_PAD + 2048 + h * 16 + n];
        Cs[i][n] = b2f(cb);
        Bm[i][n] = b2f(bb);
        Bt[n][i] = bb;
    }
    __syncthreads();   // dt/wk + C/B ready
#pragma unroll
    for (int it = 0; it < 2; ++it) {
        int li = it * 256 + tid;
        int j = li & 63, p0 = (li >> 6) * 8;
        u16x8 xv = *(const u16x8*)&proj[(tok0 + j) * PROJ_PAD + h * 64 + p0];
        float w = wk[j];
#pragma unroll
        for (int t = 0; t < 8; ++t) {
            u16 xb = xv[t];
            Xt[p0 + t][j] = xb;
            float v = w * b2f(xb);
            u16 hi = f2b(v);
            Wh[p0 + t][j] = hi;
            Wl[p0 + t][j] = f2b(v - b2f(hi));
        }
    }
    {
        int j = tid & 63, i0 = tid >> 6;
#pragma unroll
        for (int g = 0; g < 16; ++g) {
            int i = i0 + g * 4;
            float v = 0.f;
            if (j <= i) {
                float d = 0.f;
                const f32x4* cp = (const f32x4*)Cs[i];
                const f32x4* bp = (const f32x4*)Bm[j];
#pragma unroll
                for (int n4 = 0; n4 < 4; ++n4) {
                    f32x4 c = cp[n4], b = bp[n4];
                    d += c.x * b.x + c.y * b.y + c.z * b.z + c.w * b.w;
                }
                v = d * __expf(dAs[i] - dAs[j]) * dts[j];
            }
            u16 hi = f2b(v);
            Sh[i][j] = hi;
            Sl[i][j] = f2b(v - b2f(hi));
        }
    }
    __syncthreads();
    {
        f32x4 yv[4];
#pragma unroll
        for (int jt = 0; jt < 4; ++jt) yv[jt] = (f32x4){0.f, 0.f, 0.f, 0.f};
#pragma unroll
        for (int ks = 0; ks < 2; ++ks) {
            int kc = ks * 32 + quad * 8;
            short8 ah = *(const short8*)&Sh[wave * 16 + m_l][kc];
            short8 al = *(const short8*)&Sl[wave * 16 + m_l][kc];
#pragma unroll
            for (int jt = 0; jt < 4; ++jt) {
                short8 bx = *(const short8*)&Xt[jt * 16 + m_l][kc];
                yv[jt] = MFMA_B16(ah, bx, yv[jt], 0, 0, 0);
                yv[jt] = MFMA_B16(al, bx, yv[jt], 0, 0, 0);
            }
        }
#pragma unroll
        for (int jt = 0; jt < 4; ++jt)
#pragma unroll
            for (int r = 0; r < 4; ++r) {
                int i = wave * 16 + quad * 4 + r;
                int p = jt * 16 + m_l;
                y_acc[(tok0 + i) * 1024 + h * 64 + p] = f2b(yv[jt][r]);
            }
    }
    {
        f32x4 cacc = (f32x4){0.f, 0.f, 0.f, 0.f};
#pragma unroll
        for (int ks = 0; ks < 2; ++ks) {
            int kc = ks * 32 + quad * 8;
            short8 a = *(const short8*)&Bt[m_l][kc];
            short8 bh = *(const short8*)&Wh[wave * 16 + m_l][kc];
            short8 bl = *(const short8*)&Wl[wave * 16 + m_l][kc];
            cacc = MFMA_B16(a, bh, cacc, 0, 0, 0);
            cacc = MFMA_B16(a, bl, cacc, 0, 0, 0);
        }
#pragma unroll
        for (int r = 0; r < 4; ++r) {
            int n = quad * 4 + r;
            int p = wave * 16 + m_l;
            cstate[(long)bch * 1024 + n * 64 + p] = cacc[r];
        }
    }
}

// ---------------- sequential scan over chunks ----------------
__global__ __launch_bounds__(256) void scan_chunks(const float* __restrict__ cs,
                                                   const float* __restrict__ decay,
                                                   float* __restrict__ hs) {
    int t = blockIdx.x * 256 + threadIdx.x;
    int p = t & 63, n = (t >> 6) & 15, h = (t >> 10) & 15, b = t >> 14;
    float state = 0.f;
    for (int c = 0; c < 64; ++c) {
        long idx = (((long)((b * 64 + c) * 16 + h)) * 16 + n) * 64 + p;
        hs[idx] = state;
        state = decay[(b * 64 + c) * 16 + h] * state + cs[idx];
    }
}

// ---------------- y_cross + skip ----------------
__global__ __launch_bounds__(256) void ssm_cross(const u16* __restrict__ proj,
                                                 const float* __restrict__ dAcs,
                                                 const float* __restrict__ hs,
                                                 const u16* __restrict__ y_acc,
                                                 const float* __restrict__ D_param,
                                                 u16* __restrict__ y_pre) {
    int bch = blockIdx.x;
    int bc = bch >> 4, h = bch & 15;
    long tok0 = (long)bc * 64;
    __shared__ float hss[16][64], Cs[64][16], dAs[64];
    int tid = threadIdx.x;
#pragma unroll
    for (int it = 0; it < 4; ++it) {
        int li = it * 256 + tid;
        hss[li >> 6][li & 63] = hs[(long)bch * 1024 + li];
        int i = li >> 4, n = li & 15;
        Cs[i][n] = b2f(proj[(tok0 + i) * PROJ_PAD + 2304 + h * 16 + n]);
    }
    if (tid < 64) dAs[tid] = dAcs[(tok0 + tid) * 16 + h];
    __syncthreads();
    float Dh = D_param[h];
    int pi = (tid & 15) * 4;
    int ib = tid >> 4;
#pragma unroll
    for (int g = 0; g < 4; ++g) {
        int i = ib + 16 * g;
        f32x4 cr = (f32x4){0.f, 0.f, 0.f, 0.f};
#pragma unroll
        for (int n = 0; n < 16; ++n) {
            float c = Cs[i][n];
            cr += c * *(const f32x4*)&hss[n][pi];
        }
        float e = __expf(dAs[i]);
        long off = (tok0 + i) * 1024 + h * 64 + pi;
        u16x4 ya = *(const u16x4*)&y_acc[off];
        u16x4 xv = *(const u16x4*)&proj[(tok0 + i) * PROJ_PAD + h * 64 + pi];
        u16x4 o;
        o.x = f2b(b2f(ya.x) + e * cr.x + b2f(xv.x) * Dh);
        o.y = f2b(b2f(ya.y) + e * cr.y + b2f(xv.y) * Dh);
        o.z = f2b(b2f(ya.z) + e * cr.z + b2f(xv.z) * Dh);
        o.w = f2b(b2f(ya.w) + e * cr.w + b2f(xv.w) * Dh);
        *(u16x4*)&y_pre[off] = o;
    }
}

// ---------------- RMSNorm + SiLU gate (in place on y_pre) ----------------
__global__ __launch_bounds__(256) void norm_gate(const u16* __restrict__ proj,
                                                 const float* __restrict__ norm_w,
                                                 u16* __restrict__ y) {
    long tok = blockIdx.x;
    int tid = threadIdx.x;
    int c0 = tid * 4;
    u16x4 yv = *(const u16x4*)&y[tok * 1024 + c0];
    float v0 = b2f(yv.x), v1 = b2f(yv.y), v2 = b2f(yv.z), v3 = b2f(yv.w);
    float ss = v0 * v0 + v1 * v1 + v2 * v2 + v3 * v3;
    int lane = tid & 63, w = tid >> 6;
#pragma unroll
    for (int d = 32; d > 0; d >>= 1) ss += __shfl_down(ss, d, 64);
    __shared__ float red[4];
    if (lane == 0) red[w] = ss;
    __syncthreads();
    float tot = red[0] + red[1] + red[2] + red[3];
    float inv = rsqrtf(tot * (1.f / 1024.f) + 1e-6f);
    float4 nw = *(const float4*)&norm_w[c0];
    u16x4 zv = *(const u16x4*)&proj[tok * PROJ_PAD + 1024 + c0];
    float z0 = b2f(zv.x), z1 = b2f(zv.y), z2 = b2f(zv.z), z3 = b2f(zv.w);
    u16x4 o;
    o.x = f2b(v0 * inv * nw.x * (z0 / (1.f + __expf(-z0))));
    o.y = f2b(v1 * inv * nw.y * (z1 / (1.f + __expf(-z1))));
    o.z = f2b(v2 * inv * nw.z * (z2 / (1.f + __expf(-z2))));
    o.w = f2b(v3 * inv * nw.w * (z3 / (1.f + __expf(-z3))));
    *(u16x4*)&y[tok * 1024 + c0] = o;
}

extern "C" void kernel_launch(void* const* d_in, const int* in_sizes, int n_in,
                              void* d_out, int out_size, void* d_ws, size_t ws_size,
                              hipStream_t stream) {
    const float* x      = (const float*)d_in[0];
    const float* W_in   = (const float*)d_in[1];
    const float* dt_W   = (const float*)d_in[2];
    const float* dt_b   = (const float*)d_in[3];
    const float* A_log  = (const float*)d_in[4];
    const float* D_par  = (const float*)d_in[5];
    const float* W_out  = (const float*)d_in[6];
    const float* norm_w = (const float*)d_in[7];
    float* out = (float*)d_out;

    char* ws = (char*)d_ws;
    size_t off = 0;
    auto alloc = [&](size_t b) { void* p = ws + off; off += (b + 255) & ~(size_t)255; return p; };
    u16*   x_bf    = (u16*)alloc((size_t)BTOK * DK * 2);
    u16*   win_bf  = (u16*)alloc((size_t)PROJ_PAD * DK * 2);
    u16*   wout_bf = (u16*)alloc((size_t)DK * DK * 2);
    u16*   proj    = (u16*)alloc((size_t)BTOK * PROJ_PAD * 2);
    float* dAcs    = (float*)alloc((size_t)BTOK * NH * 4);
    float* decay   = (float*)alloc((size_t)NCH * NH * 4);
    float* cstate  = (float*)alloc((size_t)NCH * NH * NS * HD * 4);
    float* hstates = (float*)alloc((size_t)NCH * NH * NS * HD * 4);
    u16*   y_pre   = (u16*)alloc((size_t)BTOK * DK * 2);
    u16*   y_acc   = x_bf;  // alias: x_bf dead after GEMM1 (stream-ordered)

    cast_bf16<<<BTOK * DK / 4 / 256, 256, 0, stream>>>(x, x_bf, BTOK * DK / 4);
    cast_bf16<<<DK * DK / 4 / 256, 256, 0, stream>>>(W_out, wout_bf, DK * DK / 4);
    cast_pad_win<<<PROJ_PAD * DK / 4 / 256, 256, 0, stream>>>(W_in, win_bf);

    // GEMM1: 16384 x 2688 x 1024 -> proj (bf16), grid 64*21 = 1344 (%64==0)
    gemmf<1><<<dim3(MT * (PROJ_PAD / 128)), 256, 0, stream>>>(x_bf, win_bf, nullptr, proj, DK, PROJ_PAD);

    ssm_intra<<<NCH * NH, 256, 0, stream>>>(proj, dt_W, dt_b, A_log, dAcs, decay, y_acc, cstate);
    scan_chunks<<<256, 256, 0, stream>>>(cstate, decay, hstates);
    ssm_cross<<<NCH * NH, 256, 0, stream>>>(proj, dAcs, hstates, y_acc, D_par, y_pre);
    norm_gate<<<BTOK, 256, 0, stream>>>(proj, norm_w, y_pre);

    // GEMM2: 16384 x 1024 x 1024 -> out (fp32), grid 64*8 = 512 (%64==0)
    gemmf<0><<<dim3(MT * (DK / 128)), 256, 0, stream>>>(y_pre, wout_bf, out, nullptr, DK, DK);
}

// Round 8
// 390.890 us; speedup vs baseline: 1.3971x; 1.3971x over previous
//
#include <hip/hip_runtime.h>

typedef unsigned short u16;
typedef __attribute__((ext_vector_type(8))) short short8;   // 8 bf16 (4 VGPRs) MFMA frag
typedef __attribute__((ext_vector_type(4))) float f32x4;
typedef __attribute__((ext_vector_type(4))) unsigned short u16x4;
typedef __attribute__((ext_vector_type(8))) unsigned short u16x8;

#define BTOK 16384      // B*S = 4*4096
#define PROJ_N 2576
#define PROJ_PAD 2816   // 11 * 256 (GEMM1 N 256-divisible; R5-verbatim)
#define DK 1024         // D_MODEL = D_INNER
#define NCH 256         // B * nChunks = 4*64
#define NH 16
#define HD 64
#define NS 16           // D_STATE

__device__ __forceinline__ float b2f(u16 b) {
    union { unsigned int u; float f; } v; v.u = ((unsigned int)b) << 16; return v.f;
}
__device__ __forceinline__ u16 f2b(float f) {
    union { float f; unsigned int u; } v; v.f = f;
    unsigned int r = v.u + 0x7fffu + ((v.u >> 16) & 1u);
    return (u16)(r >> 16);
}

// Inline-asm global->LDS staging (16B/lane), invisible to the waitcnt pass.
// LDS dest = M0 (wave-uniform byte offset via readfirstlane) + lane*16.
__device__ __forceinline__ void stage_asm(const u16* g, const u16* l) {
    unsigned loff = (unsigned)(size_t)(const __attribute__((address_space(3))) u16*)l;
    unsigned su = __builtin_amdgcn_readfirstlane(loff);
    asm volatile("s_mov_b32 m0, %1\n\t"
                 "global_load_lds_dwordx4 %0, off"
                 :: "v"(g), "s"(su));
}

// Inline-asm ds_read_b128, invisible. Ordering vs MFMA via counted lgkmcnt +
// sched_barrier(0) (rule #18). DS ops complete in-order per wave.
template <int IMM>
__device__ __forceinline__ short8 dsr128(unsigned a) {
    short8 d;
    asm volatile("ds_read_b128 %0, %1 offset:%2" : "=v"(d) : "v"(a), "i"(IMM));
    return d;
}

#define LGKM(n) do { asm volatile("s_waitcnt lgkmcnt(" #n ")"); __builtin_amdgcn_sched_barrier(0); } while (0)
#define MFMA_B16 __builtin_amdgcn_mfma_f32_16x16x32_bf16

// ---------------- casts ----------------
__global__ __launch_bounds__(256) void cast_bf16(const float* __restrict__ s,
                                                 u16* __restrict__ d, int n4) {
    int t = blockIdx.x * 256 + threadIdx.x;
    if (t < n4) {
        float4 v = ((const float4*)s)[t];
        u16x4 o; o.x = f2b(v.x); o.y = f2b(v.y); o.z = f2b(v.z); o.w = f2b(v.w);
        ((u16x4*)d)[t] = o;
    }
}

__global__ __launch_bounds__(256) void cast_pad_win(const float* __restrict__ s,
                                                    u16* __restrict__ d) {
    int t = blockIdx.x * 256 + threadIdx.x;
    int i4 = t * 4;
    float4 v = make_float4(0.f, 0.f, 0.f, 0.f);
    if (i4 < PROJ_N * DK) v = ((const float4*)s)[t];
    u16x4 o; o.x = f2b(v.x); o.y = f2b(v.y); o.z = f2b(v.z); o.w = f2b(v.w);
    ((u16x4*)d)[t] = o;
}

// ---------------- 256x256 GEMM, one-phase-ahead read pipeline (R5-verbatim) ----------
// Best measured GEMM variant: 103.7us GEMM1, MfmaUtil 38.7% (R5).
#define MT 64   // M/256 for both GEMMs (M = 16384)

template <int OUT_BF16>
__global__ __launch_bounds__(512, 2) void gemmk(const u16* __restrict__ A,
                                                const u16* __restrict__ B,
                                                float* __restrict__ Cf,
                                                u16* __restrict__ Cb,
                                                int K, int ldc) {
    extern __shared__ u16 smem[];
    u16* AsU = smem;            // 2 bufs x 256x64 u16 A; B at +32768 u16
    const int tid = threadIdx.x;
    const int wave = tid >> 6, lane = tid & 63;
    const int wr = wave >> 2, wc = wave & 3;
    const int m_l = lane & 15, quad = lane >> 4;

    const int b = blockIdx.x;                 // gridDim.x % 64 == 0 for both launches
    const int bm = (b & 7) * 8 + ((b >> 3) & 7);
    const int bn = b >> 6;

    const u16* Ab = A + (long)bm * 256 * K;
    const u16* Bb = B + (long)bn * 256 * K;

    const unsigned lds0 = (unsigned)(size_t)(const __attribute__((address_space(3))) u16*)smem;
    const int sw = m_l & 7;
    const unsigned a0b = lds0 + (wr * 128 + m_l) * 128 + (quad ^ sw) * 16;        // kstep0
    const unsigned a1b = lds0 + (wr * 128 + m_l) * 128 + ((4 + quad) ^ sw) * 16;  // kstep1
    const unsigned b0b = lds0 + 65536 + (wc * 64 + m_l) * 128 + (quad ^ sw) * 16;
    const unsigned b1b = lds0 + 65536 + (wc * 64 + m_l) * 128 + ((4 + quad) ^ sw) * 16;

    const int srow = tid >> 3;
    const int schk = (tid & 7) ^ (srow & 7);
    const int sdst = wave * 512;

    f32x4 acc[8][4];
#pragma unroll
    for (int f = 0; f < 8; ++f)
#pragma unroll
        for (int n = 0; n < 4; ++n) acc[f][n] = (f32x4){0.f, 0.f, 0.f, 0.f};

    const int NT = K >> 6;

    auto stage = [&](const u16* G, u16* L, int q, int k0) {
        stage_asm(G + (long)(q * 64 + srow) * K + k0 + schk * 8,
                  L + q * 4096 + sdst);
    };
    u16* BsU = smem + 32768;

    stage(Ab, AsU, 0, 0); stage(Ab, AsU, 1, 0); stage(Ab, AsU, 2, 0); stage(Ab, AsU, 3, 0);
    stage(Bb, BsU, 0, 0); stage(Bb, BsU, 1, 0); stage(Bb, BsU, 2, 0); stage(Bb, BsU, 3, 0);
    asm volatile("s_waitcnt vmcnt(0)");
    __builtin_amdgcn_s_barrier();

    short8 afX[4], afY[4], bfX[4], bfY[4];
    afX[0] = dsr128<0>(a0b);    afX[1] = dsr128<2048>(a0b);
    afX[2] = dsr128<4096>(a0b); afX[3] = dsr128<6144>(a0b);
    bfX[0] = dsr128<0>(b0b);    bfX[1] = dsr128<2048>(b0b);
    bfX[2] = dsr128<4096>(b0b); bfX[3] = dsr128<6144>(b0b);

    int cur = 0;
    for (int t = 0; t < NT; ++t) {
        const unsigned cB = ((unsigned)cur) << 15;
        const unsigned a0 = a0b + cB, a1 = a1b + cB, b0 = b0b + cB, b1 = b1b + cB;
        const int nbu = (cur << 14) ^ 16384;
        u16* Anxt = AsU + nbu;
        u16* Bnxt = BsU + nbu;
        const int k1 = (t + 1) << 6;
        const bool s1 = (t + 1 < NT);

        // p0: stage A q0,q1; issue afY; lgkm(4); MFMA (Mlo,ks0)
        if (s1) { stage(Ab, Anxt, 0, k1); stage(Ab, Anxt, 1, k1); }
        afY[0] = dsr128<8192>(a0);  afY[1] = dsr128<10240>(a0);
        afY[2] = dsr128<12288>(a0); afY[3] = dsr128<14336>(a0);
        LGKM(4);
        __builtin_amdgcn_s_setprio(1);
#pragma unroll
        for (int f = 0; f < 4; ++f)
#pragma unroll
            for (int n = 0; n < 4; ++n)
                acc[f][n] = MFMA_B16(afX[f], bfX[n], acc[f][n], 0, 0, 0);
        __builtin_amdgcn_s_setprio(0);

        // p1: stage A q2,q3; issue afX(ks1), bfY; lgkm(8); MFMA (Mhi,ks0)
        if (s1) { stage(Ab, Anxt, 2, k1); stage(Ab, Anxt, 3, k1); }
        afX[0] = dsr128<0>(a1);    afX[1] = dsr128<2048>(a1);
        afX[2] = dsr128<4096>(a1); afX[3] = dsr128<6144>(a1);
        bfY[0] = dsr128<0>(b1);    bfY[1] = dsr128<2048>(b1);
        bfY[2] = dsr128<4096>(b1); bfY[3] = dsr128<6144>(b1);
        LGKM(8);
        __builtin_amdgcn_s_setprio(1);
#pragma unroll
        for (int f = 0; f < 4; ++f)
#pragma unroll
            for (int n = 0; n < 4; ++n)
                acc[4 + f][n] = MFMA_B16(afY[f], bfX[n], acc[4 + f][n], 0, 0, 0);
        __builtin_amdgcn_s_setprio(0);

        // p2: stage B q0,q1; issue afY(ks1); lgkm(4); MFMA (Mlo,ks1)
        if (s1) { stage(Bb, Bnxt, 0, k1); stage(Bb, Bnxt, 1, k1); }
        afY[0] = dsr128<8192>(a1);  afY[1] = dsr128<10240>(a1);
        afY[2] = dsr128<12288>(a1); afY[3] = dsr128<14336>(a1);
        LGKM(4);
        __builtin_amdgcn_s_setprio(1);
#pragma unroll
        for (int f = 0; f < 4; ++f)
#pragma unroll
            for (int n = 0; n < 4; ++n)
                acc[f][n] = MFMA_B16(afX[f], bfY[n], acc[f][n], 0, 0, 0);
        __builtin_amdgcn_s_setprio(0);

        // p3: stage B q2,q3; lgkm(0); MFMA (Mhi,ks1)
        if (s1) { stage(Bb, Bnxt, 2, k1); stage(Bb, Bnxt, 3, k1); }
        LGKM(0);
        __builtin_amdgcn_s_setprio(1);
#pragma unroll
        for (int f = 0; f < 4; ++f)
#pragma unroll
            for (int n = 0; n < 4; ++n)
                acc[4 + f][n] = MFMA_B16(afY[f], bfY[n], acc[4 + f][n], 0, 0, 0);
        __builtin_amdgcn_s_setprio(0);
        __builtin_amdgcn_sched_barrier(0);

        // tile boundary
        if (s1) {
            asm volatile("s_waitcnt vmcnt(0)");
            __builtin_amdgcn_s_barrier();
            const unsigned nB = cB ^ 32768u;
            const unsigned na0 = a0b + nB, nb0 = b0b + nB;
            afX[0] = dsr128<0>(na0);    afX[1] = dsr128<2048>(na0);
            afX[2] = dsr128<4096>(na0); afX[3] = dsr128<6144>(na0);
            bfX[0] = dsr128<0>(nb0);    bfX[1] = dsr128<2048>(nb0);
            bfX[2] = dsr128<4096>(nb0); bfX[3] = dsr128<6144>(nb0);
        }
        cur ^= 1;
    }

    // C/D layout: col=lane&15, row=quad*4+reg (m89/m91 verified)
#pragma unroll
    for (int f = 0; f < 8; ++f) {
        int row_base = bm * 256 + wr * 128 + f * 16 + quad * 4;
#pragma unroll
        for (int n = 0; n < 4; ++n) {
            int col = bn * 256 + wc * 64 + n * 16 + m_l;
#pragma unroll
            for (int r = 0; r < 4; ++r) {
                float v = acc[f][n][r];
                long off = (long)(row_base + r) * ldc + col;
                if (OUT_BF16) Cb[off] = f2b(v);
                else          Cf[off] = v;
            }
        }
    }
}

// ---------------- intra-chunk: dt fold + scores + y_intra/cstate via MFMA ----------------
__global__ __launch_bounds__(256) void ssm_intra(const u16* __restrict__ proj,
                                                 const float* __restrict__ dt_W,
                                                 const float* __restrict__ dt_b,
                                                 const float* __restrict__ A_log,
                                                 float* __restrict__ dAcs,
                                                 float* __restrict__ decay,
                                                 u16* __restrict__ y_acc,
                                                 float* __restrict__ cstate) {
    int bch = blockIdx.x;             // (b*64+c)*16 + h
    int bc = bch >> 4, h = bch & 15;
    long tok0 = (long)bc * 64;
    __shared__ float Cs[64][20], Bm[64][20];
    __shared__ u16 Sh[64][72], Sl[64][72];
    __shared__ u16 Xt[64][72];
    __shared__ u16 Wh[64][72], Wl[64][72];
    __shared__ u16 Bt[16][72];
    __shared__ float dts[64], dAs[64], wk[64];
    const int tid = threadIdx.x;
    const int wave = tid >> 6, lane = tid & 63;
    const int m_l = lane & 15, quad = lane >> 4;

    if (tid < 64) {
        long tok = tok0 + tid;
        u16x8 lo0 = *(const u16x8*)&proj[tok * PROJ_PAD + 2560];
        u16x8 lo1 = *(const u16x8*)&proj[tok * PROJ_PAD + 2568];
        float a = dt_b[h];
#pragma unroll
        for (int r = 0; r < 8; ++r) a += b2f(lo0[r]) * dt_W[h * 16 + r];
#pragma unroll
        for (int r = 0; r < 8; ++r) a += b2f(lo1[r]) * dt_W[h * 16 + 8 + r];
        float d = (a > 20.f) ? a : log1pf(__expf(a));
        float dA = -__expf(A_log[h]) * d;
        float cs = dA;
#pragma unroll
        for (int off = 1; off < 64; off <<= 1) {
            float o = __shfl_up(cs, off, 64);
            if (tid >= off) cs += o;
        }
        float cs63 = __shfl(cs, 63, 64);
        dts[tid] = d;
        dAs[tid] = cs;
        wk[tid] = d * __expf(cs63 - cs);
        dAcs[tok * 16 + h] = cs;
        if (tid == 63) decay[bc * 16 + h] = __expf(cs);
    }
#pragma unroll
    for (int it = 0; it < 4; ++it) {
        int li = it * 256 + tid;
        int i = li >> 4, n = li & 15;
        u16 cb = proj[(tok0 + i) * PROJ_PAD + 2304 + h * 16 + n];
        u16 bb = proj[(tok0 + i) * PROJ_PAD + 2048 + h * 16 + n];
        Cs[i][n] = b2f(cb);
        Bm[i][n] = b2f(bb);
        Bt[n][i] = bb;
    }
    __syncthreads();   // dt/wk + C/B ready
#pragma unroll
    for (int it = 0; it < 2; ++it) {
        int li = it * 256 + tid;
        int j = li & 63, p0 = (li >> 6) * 8;
        u16x8 xv = *(const u16x8*)&proj[(tok0 + j) * PROJ_PAD + h * 64 + p0];
        float w = wk[j];
#pragma unroll
        for (int t = 0; t < 8; ++t) {
            u16 xb = xv[t];
            Xt[p0 + t][j] = xb;
            float v = w * b2f(xb);
            u16 hi = f2b(v);
            Wh[p0 + t][j] = hi;
            Wl[p0 + t][j] = f2b(v - b2f(hi));
        }
    }
    {
        int j = tid & 63, i0 = tid >> 6;
#pragma unroll
        for (int g = 0; g < 16; ++g) {
            int i = i0 + g * 4;
            float v = 0.f;
            if (j <= i) {
                float d = 0.f;
                const f32x4* cp = (const f32x4*)Cs[i];
                const f32x4* bp = (const f32x4*)Bm[j];
#pragma unroll
                for (int n4 = 0; n4 < 4; ++n4) {
                    f32x4 c = cp[n4], b = bp[n4];
                    d += c.x * b.x + c.y * b.y + c.z * b.z + c.w * b.w;
                }
                v = d * __expf(dAs[i] - dAs[j]) * dts[j];
            }
            u16 hi = f2b(v);
            Sh[i][j] = hi;
            Sl[i][j] = f2b(v - b2f(hi));
        }
    }
    __syncthreads();
    {
        f32x4 yv[4];
#pragma unroll
        for (int jt = 0; jt < 4; ++jt) yv[jt] = (f32x4){0.f, 0.f, 0.f, 0.f};
#pragma unroll
        for (int ks = 0; ks < 2; ++ks) {
            int kc = ks * 32 + quad * 8;
            short8 ah = *(const short8*)&Sh[wave * 16 + m_l][kc];
            short8 al = *(const short8*)&Sl[wave * 16 + m_l][kc];
#pragma unroll
            for (int jt = 0; jt < 4; ++jt) {
                short8 bx = *(const short8*)&Xt[jt * 16 + m_l][kc];
                yv[jt] = MFMA_B16(ah, bx, yv[jt], 0, 0, 0);
                yv[jt] = MFMA_B16(al, bx, yv[jt], 0, 0, 0);
            }
        }
#pragma unroll
        for (int jt = 0; jt < 4; ++jt)
#pragma unroll
            for (int r = 0; r < 4; ++r) {
                int i = wave * 16 + quad * 4 + r;
                int p = jt * 16 + m_l;
                y_acc[(tok0 + i) * 1024 + h * 64 + p] = f2b(yv[jt][r]);
            }
    }
    {
        f32x4 cacc = (f32x4){0.f, 0.f, 0.f, 0.f};
#pragma unroll
        for (int ks = 0; ks < 2; ++ks) {
            int kc = ks * 32 + quad * 8;
            short8 a = *(const short8*)&Bt[m_l][kc];
            short8 bh = *(const short8*)&Wh[wave * 16 + m_l][kc];
            short8 bl = *(const short8*)&Wl[wave * 16 + m_l][kc];
            cacc = MFMA_B16(a, bh, cacc, 0, 0, 0);
            cacc = MFMA_B16(a, bl, cacc, 0, 0, 0);
        }
#pragma unroll
        for (int r = 0; r < 4; ++r) {
            int n = quad * 4 + r;
            int p = wave * 16 + m_l;
            cstate[(long)bch * 1024 + n * 64 + p] = cacc[r];
        }
    }
}

// ---------------- sequential scan over chunks ----------------
__global__ __launch_bounds__(256) void scan_chunks(const float* __restrict__ cs,
                                                   const float* __restrict__ decay,
                                                   float* __restrict__ hs) {
    int t = blockIdx.x * 256 + threadIdx.x;
    int p = t & 63, n = (t >> 6) & 15, h = (t >> 10) & 15, b = t >> 14;
    float state = 0.f;
    for (int c = 0; c < 64; ++c) {
        long idx = (((long)((b * 64 + c) * 16 + h)) * 16 + n) * 64 + p;
        hs[idx] = state;
        state = decay[(b * 64 + c) * 16 + h] * state + cs[idx];
    }
}

// ---------------- fused y_cross + skip + RMSNorm + SiLU gate ----------------
// Block = one chunk (64 tokens, all 16 heads), 1024 thr (wave w == head w).
// Replaces ssm_cross + norm_gate: keeps pre-norm y in regs (bf16, preserving
// the old kernels' rounding exactly) -> saves the 64MB y_pre HBM round-trip.
// LDS: hss [16h][16n][64p] f32 (64KB, reads broadcast/2-way), Csl [64i][16h][16n]
// u16 (32KB, hh-fastest so the cooperative write is conflict-free, reads
// broadcast), dAe/ssl [64][17] f32 (padded), inv [64].
#define CN_LDS (65536 + 32768 + 4352 + 4352 + 256)

__global__ __launch_bounds__(1024, 1) void cross_norm(const u16* __restrict__ proj,
                                                      const float* __restrict__ dAcs,
                                                      const float* __restrict__ hs,
                                                      const u16* __restrict__ y_acc,
                                                      const float* __restrict__ D_param,
                                                      const float* __restrict__ norm_w,
                                                      u16* __restrict__ y) {
    extern __shared__ char cnl[];
    float* hss  = (float*)cnl;                       // [16][16][64]
    u16*   Csl  = (u16*)(cnl + 65536);               // [64][16][16]
    float* dAe  = (float*)(cnl + 65536 + 32768);     // [64][17]
    float* ssl  = dAe + 64 * 17;                     // [64][17]
    float* invv = ssl + 64 * 17;                     // [64]
    const int bc = blockIdx.x;
    const long tok0 = (long)bc * 64;
    const int tid = threadIdx.x;
    const int h = tid >> 6, l = tid & 63;

    {   // hss: coalesced, layout matches hs flat [h][n][p]
        long base = (long)bc * 16384;
#pragma unroll
        for (int it = 0; it < 16; ++it)
            hss[it * 1024 + tid] = hs[base + it * 1024 + tid];
    }
    {   // C + exp(dA): thread (i = tid>>4, hh = tid&15)
        int i = tid >> 4, hh = tid & 15;
        const u16* cp = &proj[(tok0 + i) * PROJ_PAD + 2304 + hh * 16];
        u16x8 c0 = *(const u16x8*)cp;
        u16x8 c1 = *(const u16x8*)(cp + 8);
        *(u16x8*)&Csl[(i * 16 + hh) * 16] = c0;
        *(u16x8*)&Csl[(i * 16 + hh) * 16 + 8] = c1;
        dAe[i * 17 + hh] = __expf(dAcs[(tok0 + i) * 16 + hh]);
    }
    __syncthreads();

    const float Dh = D_param[h];
    const int pi = (l & 15) * 4;
    const int ib = l >> 4;                 // 0..3
    u16x4 yv[16];

#pragma unroll
    for (int g = 0; g < 16; ++g) {
        int i = ib + 4 * g;                // 0..63
        f32x4 cr = (f32x4){0.f, 0.f, 0.f, 0.f};
        const u16* Cp = &Csl[(i * 16 + h) * 16];
#pragma unroll
        for (int n = 0; n < 16; ++n)
            cr += b2f(Cp[n]) * *(const f32x4*)&hss[(h * 16 + n) * 64 + pi];
        float e = dAe[i * 17 + h];
        long off = (tok0 + i) * 1024 + h * 64 + pi;
        u16x4 ya = *(const u16x4*)&y_acc[off];
        u16x4 xv = *(const u16x4*)&proj[(tok0 + i) * PROJ_PAD + h * 64 + pi];
        u16x4 o;
        o.x = f2b(b2f(ya.x) + e * cr.x + b2f(xv.x) * Dh);
        o.y = f2b(b2f(ya.y) + e * cr.y + b2f(xv.y) * Dh);
        o.z = f2b(b2f(ya.z) + e * cr.z + b2f(xv.z) * Dh);
        o.w = f2b(b2f(ya.w) + e * cr.w + b2f(xv.w) * Dh);
        yv[g] = o;
        float v0 = b2f(o.x), v1 = b2f(o.y), v2 = b2f(o.z), v3 = b2f(o.w);
        float ss = v0 * v0 + v1 * v1 + v2 * v2 + v3 * v3;
        // reduce over the 16-lane subgroup (same token, this head's 64 ch)
#pragma unroll
        for (int d = 1; d < 16; d <<= 1) ss += __shfl_xor(ss, d, 16);
        if ((l & 15) == 0) ssl[i * 17 + h] = ss;
    }
    __syncthreads();
    if (tid < 64) {
        float s = 0.f;
#pragma unroll
        for (int hh = 0; hh < 16; ++hh) s += ssl[tid * 17 + hh];
        invv[tid] = rsqrtf(s * (1.f / 1024.f) + 1e-6f);
    }
    __syncthreads();

    const float4 nw = *(const float4*)&norm_w[h * 64 + pi];
#pragma unroll
    for (int g = 0; g < 16; ++g) {
        int i = ib + 4 * g;
        float inv = invv[i];
        long off = (tok0 + i) * 1024 + h * 64 + pi;
        u16x4 zv = *(const u16x4*)&proj[(tok0 + i) * PROJ_PAD + 1024 + h * 64 + pi];
        float z0 = b2f(zv.x), z1 = b2f(zv.y), z2 = b2f(zv.z), z3 = b2f(zv.w);
        u16x4 o;
        o.x = f2b(b2f(yv[g].x) * inv * nw.x * (z0 / (1.f + __expf(-z0))));
        o.y = f2b(b2f(yv[g].y) * inv * nw.y * (z1 / (1.f + __expf(-z1))));
        o.z = f2b(b2f(yv[g].z) * inv * nw.z * (z2 / (1.f + __expf(-z2))));
        o.w = f2b(b2f(yv[g].w) * inv * nw.w * (z3 / (1.f + __expf(-z3))));
        *(u16x4*)&y[off] = o;
    }
}

extern "C" void kernel_launch(void* const* d_in, const int* in_sizes, int n_in,
                              void* d_out, int out_size, void* d_ws, size_t ws_size,
                              hipStream_t stream) {
    const float* x      = (const float*)d_in[0];
    const float* W_in   = (const float*)d_in[1];
    const float* dt_W   = (const float*)d_in[2];
    const float* dt_b   = (const float*)d_in[3];
    const float* A_log  = (const float*)d_in[4];
    const float* D_par  = (const float*)d_in[5];
    const float* W_out  = (const float*)d_in[6];
    const float* norm_w = (const float*)d_in[7];
    float* out = (float*)d_out;

    char* ws = (char*)d_ws;
    size_t off = 0;
    auto alloc = [&](size_t b) { void* p = ws + off; off += (b + 255) & ~(size_t)255; return p; };
    u16*   x_bf    = (u16*)alloc((size_t)BTOK * DK * 2);
    u16*   win_bf  = (u16*)alloc((size_t)PROJ_PAD * DK * 2);
    u16*   wout_bf = (u16*)alloc((size_t)DK * DK * 2);
    u16*   proj    = (u16*)alloc((size_t)BTOK * PROJ_PAD * 2);
    float* dAcs    = (float*)alloc((size_t)BTOK * NH * 4);
    float* decay   = (float*)alloc((size_t)NCH * NH * 4);
    float* cstate  = (float*)alloc((size_t)NCH * NH * NS * HD * 4);
    float* hstates = (float*)alloc((size_t)NCH * NH * NS * HD * 4);
    u16*   y_pre   = (u16*)alloc((size_t)BTOK * DK * 2);
    u16*   y_acc   = x_bf;  // alias: x_bf dead after GEMM1 (stream-ordered)

    static bool attr_done = false;
    if (!attr_done) {
        (void)hipFuncSetAttribute(reinterpret_cast<const void*>(&gemmk<1>),
                                  hipFuncAttributeMaxDynamicSharedMemorySize, 131072);
        (void)hipFuncSetAttribute(reinterpret_cast<const void*>(&gemmk<0>),
                                  hipFuncAttributeMaxDynamicSharedMemorySize, 131072);
        (void)hipFuncSetAttribute(reinterpret_cast<const void*>(&cross_norm),
                                  hipFuncAttributeMaxDynamicSharedMemorySize, CN_LDS);
        attr_done = true;
    }

    cast_bf16<<<BTOK * DK / 4 / 256, 256, 0, stream>>>(x, x_bf, BTOK * DK / 4);
    cast_bf16<<<DK * DK / 4 / 256, 256, 0, stream>>>(W_out, wout_bf, DK * DK / 4);
    cast_pad_win<<<PROJ_PAD * DK / 4 / 256, 256, 0, stream>>>(W_in, win_bf);

    // GEMM1: 16384 x 2816 x 1024 -> proj (bf16), grid 64*11 = 704 (%64==0)
    gemmk<1><<<dim3(MT * (PROJ_PAD / 256)), 512, 131072, stream>>>(x_bf, win_bf, nullptr, proj, DK, PROJ_PAD);

    ssm_intra<<<NCH * NH, 256, 0, stream>>>(proj, dt_W, dt_b, A_log, dAcs, decay, y_acc, cstate);
    scan_chunks<<<256, 256, 0, stream>>>(cstate, decay, hstates);
    cross_norm<<<NCH, 1024, CN_LDS, stream>>>(proj, dAcs, hstates, y_acc, D_par, norm_w, y_pre);

    // GEMM2: 16384 x 1024 x 1024 -> out (fp32), grid 64*4 = 256 (%64==0)
    gemmk<0><<<dim3(MT * (DK / 256)), 512, 131072, stream>>>(y_pre, wout_bf, out, nullptr, DK, DK);
}

// Round 9
// 359.115 us; speedup vs baseline: 1.5207x; 1.0885x over previous
//
#include <hip/hip_runtime.h>

typedef unsigned short u16;
typedef __attribute__((ext_vector_type(8))) short short8;   // 8 bf16 (4 VGPRs) MFMA frag
typedef __attribute__((ext_vector_type(4))) float f32x4;
typedef __attribute__((ext_vector_type(16))) float f32x16;
typedef __attribute__((ext_vector_type(4))) unsigned short u16x4;
typedef __attribute__((ext_vector_type(8))) unsigned short u16x8;

#define BTOK 16384      // B*S = 4*4096
#define PROJ_N 2576
#define PROJ_PAD 2816   // 11 * 256 (GEMM1 N 256-divisible)
#define DK 1024         // D_MODEL = D_INNER
#define NCH 256         // B * nChunks = 4*64
#define NH 16
#define HD 64
#define NS 16           // D_STATE

__device__ __forceinline__ float b2f(u16 b) {
    union { unsigned int u; float f; } v; v.u = ((unsigned int)b) << 16; return v.f;
}
__device__ __forceinline__ u16 f2b(float f) {
    union { float f; unsigned int u; } v; v.f = f;
    unsigned int r = v.u + 0x7fffu + ((v.u >> 16) & 1u);
    return (u16)(r >> 16);
}

// Inline-asm global->LDS staging (16B/lane), invisible to the waitcnt pass.
// LDS dest = M0 (wave-uniform byte offset via readfirstlane) + lane*16.
__device__ __forceinline__ void stage_asm(const u16* g, const u16* l) {
    unsigned loff = (unsigned)(size_t)(const __attribute__((address_space(3))) u16*)l;
    unsigned su = __builtin_amdgcn_readfirstlane(loff);
    asm volatile("s_mov_b32 m0, %1\n\t"
                 "global_load_lds_dwordx4 %0, off"
                 :: "v"(g), "s"(su));
}

// Inline-asm ds_read_b128, invisible. Ordering vs MFMA via counted lgkmcnt +
// sched_barrier(0) (rule #18). DS ops complete in-order per wave.
template <int IMM>
__device__ __forceinline__ short8 dsr128(unsigned a) {
    short8 d;
    asm volatile("ds_read_b128 %0, %1 offset:%2" : "=v"(d) : "v"(a), "i"(IMM));
    return d;
}

#define LGKM(n) do { asm volatile("s_waitcnt lgkmcnt(" #n ")"); __builtin_amdgcn_sched_barrier(0); } while (0)
#define MFMA_B16 __builtin_amdgcn_mfma_f32_16x16x32_bf16

// ---------------- casts ----------------
__global__ __launch_bounds__(256) void cast_bf16(const float* __restrict__ s,
                                                 u16* __restrict__ d, int n4) {
    int t = blockIdx.x * 256 + threadIdx.x;
    if (t < n4) {
        float4 v = ((const float4*)s)[t];
        u16x4 o; o.x = f2b(v.x); o.y = f2b(v.y); o.z = f2b(v.z); o.w = f2b(v.w);
        ((u16x4*)d)[t] = o;
    }
}

__global__ __launch_bounds__(256) void cast_pad_win(const float* __restrict__ s,
                                                    u16* __restrict__ d) {
    int t = blockIdx.x * 256 + threadIdx.x;
    int i4 = t * 4;
    float4 v = make_float4(0.f, 0.f, 0.f, 0.f);
    if (i4 < PROJ_N * DK) v = ((const float4*)s)[t];
    u16x4 o; o.x = f2b(v.x); o.y = f2b(v.y); o.z = f2b(v.z); o.w = f2b(v.w);
    ((u16x4*)d)[t] = o;
}

// ---------------- 256x256 GEMM, one-phase-ahead read pipeline (R5-verbatim) ----------
// Best measured GEMM variant: ~102us GEMM1, MfmaUtil ~39%.
#define MT 64   // M/256 for both GEMMs (M = 16384)

template <int OUT_BF16>
__global__ __launch_bounds__(512, 2) void gemmk(const u16* __restrict__ A,
                                                const u16* __restrict__ B,
                                                float* __restrict__ Cf,
                                                u16* __restrict__ Cb,
                                                int K, int ldc) {
    extern __shared__ u16 smem[];
    u16* AsU = smem;            // 2 bufs x 256x64 u16 A; B at +32768 u16
    const int tid = threadIdx.x;
    const int wave = tid >> 6, lane = tid & 63;
    const int wr = wave >> 2, wc = wave & 3;
    const int m_l = lane & 15, quad = lane >> 4;

    const int b = blockIdx.x;                 // gridDim.x % 64 == 0 for both launches
    const int bm = (b & 7) * 8 + ((b >> 3) & 7);
    const int bn = b >> 6;

    const u16* Ab = A + (long)bm * 256 * K;
    const u16* Bb = B + (long)bn * 256 * K;

    const unsigned lds0 = (unsigned)(size_t)(const __attribute__((address_space(3))) u16*)smem;
    const int sw = m_l & 7;
    const unsigned a0b = lds0 + (wr * 128 + m_l) * 128 + (quad ^ sw) * 16;        // kstep0
    const unsigned a1b = lds0 + (wr * 128 + m_l) * 128 + ((4 + quad) ^ sw) * 16;  // kstep1
    const unsigned b0b = lds0 + 65536 + (wc * 64 + m_l) * 128 + (quad ^ sw) * 16;
    const unsigned b1b = lds0 + 65536 + (wc * 64 + m_l) * 128 + ((4 + quad) ^ sw) * 16;

    const int srow = tid >> 3;
    const int schk = (tid & 7) ^ (srow & 7);
    const int sdst = wave * 512;

    f32x4 acc[8][4];
#pragma unroll
    for (int f = 0; f < 8; ++f)
#pragma unroll
        for (int n = 0; n < 4; ++n) acc[f][n] = (f32x4){0.f, 0.f, 0.f, 0.f};

    const int NT = K >> 6;

    auto stage = [&](const u16* G, u16* L, int q, int k0) {
        stage_asm(G + (long)(q * 64 + srow) * K + k0 + schk * 8,
                  L + q * 4096 + sdst);
    };
    u16* BsU = smem + 32768;

    stage(Ab, AsU, 0, 0); stage(Ab, AsU, 1, 0); stage(Ab, AsU, 2, 0); stage(Ab, AsU, 3, 0);
    stage(Bb, BsU, 0, 0); stage(Bb, BsU, 1, 0); stage(Bb, BsU, 2, 0); stage(Bb, BsU, 3, 0);
    asm volatile("s_waitcnt vmcnt(0)");
    __builtin_amdgcn_s_barrier();

    short8 afX[4], afY[4], bfX[4], bfY[4];
    afX[0] = dsr128<0>(a0b);    afX[1] = dsr128<2048>(a0b);
    afX[2] = dsr128<4096>(a0b); afX[3] = dsr128<6144>(a0b);
    bfX[0] = dsr128<0>(b0b);    bfX[1] = dsr128<2048>(b0b);
    bfX[2] = dsr128<4096>(b0b); bfX[3] = dsr128<6144>(b0b);

    int cur = 0;
    for (int t = 0; t < NT; ++t) {
        const unsigned cB = ((unsigned)cur) << 15;
        const unsigned a0 = a0b + cB, a1 = a1b + cB, b0 = b0b + cB, b1 = b1b + cB;
        const int nbu = (cur << 14) ^ 16384;
        u16* Anxt = AsU + nbu;
        u16* Bnxt = BsU + nbu;
        const int k1 = (t + 1) << 6;
        const bool s1 = (t + 1 < NT);

        // p0: stage A q0,q1; issue afY; lgkm(4); MFMA (Mlo,ks0)
        if (s1) { stage(Ab, Anxt, 0, k1); stage(Ab, Anxt, 1, k1); }
        afY[0] = dsr128<8192>(a0);  afY[1] = dsr128<10240>(a0);
        afY[2] = dsr128<12288>(a0); afY[3] = dsr128<14336>(a0);
        LGKM(4);
        __builtin_amdgcn_s_setprio(1);
#pragma unroll
        for (int f = 0; f < 4; ++f)
#pragma unroll
            for (int n = 0; n < 4; ++n)
                acc[f][n] = MFMA_B16(afX[f], bfX[n], acc[f][n], 0, 0, 0);
        __builtin_amdgcn_s_setprio(0);

        // p1: stage A q2,q3; issue afX(ks1), bfY; lgkm(8); MFMA (Mhi,ks0)
        if (s1) { stage(Ab, Anxt, 2, k1); stage(Ab, Anxt, 3, k1); }
        afX[0] = dsr128<0>(a1);    afX[1] = dsr128<2048>(a1);
        afX[2] = dsr128<4096>(a1); afX[3] = dsr128<6144>(a1);
        bfY[0] = dsr128<0>(b1);    bfY[1] = dsr128<2048>(b1);
        bfY[2] = dsr128<4096>(b1); bfY[3] = dsr128<6144>(b1);
        LGKM(8);
        __builtin_amdgcn_s_setprio(1);
#pragma unroll
        for (int f = 0; f < 4; ++f)
#pragma unroll
            for (int n = 0; n < 4; ++n)
                acc[4 + f][n] = MFMA_B16(afY[f], bfX[n], acc[4 + f][n], 0, 0, 0);
        __builtin_amdgcn_s_setprio(0);

        // p2: stage B q0,q1; issue afY(ks1); lgkm(4); MFMA (Mlo,ks1)
        if (s1) { stage(Bb, Bnxt, 0, k1); stage(Bb, Bnxt, 1, k1); }
        afY[0] = dsr128<8192>(a1);  afY[1] = dsr128<10240>(a1);
        afY[2] = dsr128<12288>(a1); afY[3] = dsr128<14336>(a1);
        LGKM(4);
        __builtin_amdgcn_s_setprio(1);
#pragma unroll
        for (int f = 0; f < 4; ++f)
#pragma unroll
            for (int n = 0; n < 4; ++n)
                acc[f][n] = MFMA_B16(afX[f], bfY[n], acc[f][n], 0, 0, 0);
        __builtin_amdgcn_s_setprio(0);

        // p3: stage B q2,q3; lgkm(0); MFMA (Mhi,ks1)
        if (s1) { stage(Bb, Bnxt, 2, k1); stage(Bb, Bnxt, 3, k1); }
        LGKM(0);
        __builtin_amdgcn_s_setprio(1);
#pragma unroll
        for (int f = 0; f < 4; ++f)
#pragma unroll
            for (int n = 0; n < 4; ++n)
                acc[4 + f][n] = MFMA_B16(afY[f], bfY[n], acc[4 + f][n], 0, 0, 0);
        __builtin_amdgcn_s_setprio(0);
        __builtin_amdgcn_sched_barrier(0);

        // tile boundary
        if (s1) {
            asm volatile("s_waitcnt vmcnt(0)");
            __builtin_amdgcn_s_barrier();
            const unsigned nB = cB ^ 32768u;
            const unsigned na0 = a0b + nB, nb0 = b0b + nB;
            afX[0] = dsr128<0>(na0);    afX[1] = dsr128<2048>(na0);
            afX[2] = dsr128<4096>(na0); afX[3] = dsr128<6144>(na0);
            bfX[0] = dsr128<0>(nb0);    bfX[1] = dsr128<2048>(nb0);
            bfX[2] = dsr128<4096>(nb0); bfX[3] = dsr128<6144>(nb0);
        }
        cur ^= 1;
    }

    // C/D layout: col=lane&15, row=quad*4+reg (m89/m91 verified)
#pragma unroll
    for (int f = 0; f < 8; ++f) {
        int row_base = bm * 256 + wr * 128 + f * 16 + quad * 4;
#pragma unroll
        for (int n = 0; n < 4; ++n) {
            int col = bn * 256 + wc * 64 + n * 16 + m_l;
#pragma unroll
            for (int r = 0; r < 4; ++r) {
                float v = acc[f][n][r];
                long off = (long)(row_base + r) * ldc + col;
                if (OUT_BF16) Cb[off] = f2b(v);
                else          Cf[off] = v;
            }
        }
    }
}

// ---------------- intra-chunk: dt fold + MFMA scores + y_intra/cstate ----------------
// Scores phase now one mfma_f32_32x32x16_bf16 per wave (S = C.B^T, K=16 native):
// replaces 16x(8 ds_read_b128 + 16 VALU-FMA) per thread. C,B stored bf16 [64][16].
// A-op: row=lane&31, k=(lane>>5)*8+m; B-op: col=lane&31, same k (generalizes the
// verified 16x16x32 mapping). C/D: col=lane&31, row=(reg&3)+8*(reg>>2)+4*(lane>>5)
// (m74/m101 verified). LDS 59->53KB => 3 blocks/CU (was 2).
__global__ __launch_bounds__(256) void ssm_intra(const u16* __restrict__ proj,
                                                 const float* __restrict__ dt_W,
                                                 const float* __restrict__ dt_b,
                                                 const float* __restrict__ A_log,
                                                 float* __restrict__ dAcs,
                                                 float* __restrict__ decay,
                                                 u16* __restrict__ y_acc,
                                                 float* __restrict__ cstate) {
    int bch = blockIdx.x;             // (b*64+c)*16 + h
    int bc = bch >> 4, h = bch & 15;
    long tok0 = (long)bc * 64;
    __shared__ u16 Cm[64][16], Bm16[64][16];   // bf16 row-major (MFMA operands)
    __shared__ u16 Sh[64][72], Sl[64][72];     // scores hi/lo, [i][j] (A-operand layout)
    __shared__ u16 Xt[64][72];                 // X^T: [p][j]   (B-operand for y_intra)
    __shared__ u16 Wh[64][72], Wl[64][72];     // (w*X)^T hi/lo: [p][k] (B-op for cstate)
    __shared__ u16 Bt[16][72];                 // B^T: [n][k]   (A-operand for cstate)
    __shared__ float dts[64], dAs[64], wk[64];
    const int tid = threadIdx.x;
    const int wave = tid >> 6, lane = tid & 63;
    const int m_l = lane & 15, quad = lane >> 4;

    if (tid < 64) {
        long tok = tok0 + tid;
        u16x8 lo0 = *(const u16x8*)&proj[tok * PROJ_PAD + 2560];
        u16x8 lo1 = *(const u16x8*)&proj[tok * PROJ_PAD + 2568];
        float a = dt_b[h];
#pragma unroll
        for (int r = 0; r < 8; ++r) a += b2f(lo0[r]) * dt_W[h * 16 + r];
#pragma unroll
        for (int r = 0; r < 8; ++r) a += b2f(lo1[r]) * dt_W[h * 16 + 8 + r];
        float d = (a > 20.f) ? a : log1pf(__expf(a));
        float dA = -__expf(A_log[h]) * d;
        float cs = dA;
#pragma unroll
        for (int off = 1; off < 64; off <<= 1) {
            float o = __shfl_up(cs, off, 64);
            if (tid >= off) cs += o;
        }
        float cs63 = __shfl(cs, 63, 64);
        dts[tid] = d;
        dAs[tid] = cs;
        wk[tid] = d * __expf(cs63 - cs);
        dAcs[tok * 16 + h] = cs;
        if (tid == 63) decay[bc * 16 + h] = __expf(cs);
    }
#pragma unroll
    for (int it = 0; it < 4; ++it) {
        int li = it * 256 + tid;
        int i = li >> 4, n = li & 15;
        u16 cb = proj[(tok0 + i) * PROJ_PAD + 2304 + h * 16 + n];
        u16 bb = proj[(tok0 + i) * PROJ_PAD + 2048 + h * 16 + n];
        Cm[i][n] = cb;
        Bm16[i][n] = bb;
        Bt[n][i] = bb;
    }
    __syncthreads();   // dt/wk + C/B ready
#pragma unroll
    for (int it = 0; it < 2; ++it) {
        int li = it * 256 + tid;
        int j = li & 63, p0 = (li >> 6) * 8;
        u16x8 xv = *(const u16x8*)&proj[(tok0 + j) * PROJ_PAD + h * 64 + p0];
        float w = wk[j];
#pragma unroll
        for (int t = 0; t < 8; ++t) {
            u16 xb = xv[t];
            Xt[p0 + t][j] = xb;
            float v = w * b2f(xb);
            u16 hi = f2b(v);
            Wh[p0 + t][j] = hi;
            Wl[p0 + t][j] = f2b(v - b2f(hi));
        }
    }
    // scores via MFMA: wave w owns tile (it=w>>1, jt=w&1); 1 mfma 32x32x16.
    {
        const int wit = wave >> 1, wjt = wave & 1;
        const int l31 = lane & 31, lhi = lane >> 5;
        short8 af = *(const short8*)&Cm[wit * 32 + l31][lhi * 8];
        short8 bf = *(const short8*)&Bm16[wjt * 32 + l31][lhi * 8];
        f32x16 s = {};
        s = __builtin_amdgcn_mfma_f32_32x32x16_bf16(af, bf, s, 0, 0, 0);
        const int j = wjt * 32 + l31;
        const float dAj = dAs[j], dtj = dts[j];
#pragma unroll
        for (int r = 0; r < 16; ++r) {
            int i = wit * 32 + (r & 3) + 8 * (r >> 2) + 4 * lhi;
            float v = 0.f;
            if (j <= i) v = s[r] * __expf(dAs[i] - dAj) * dtj;
            u16 hi = f2b(v);
            Sh[i][j] = hi;
            Sl[i][j] = f2b(v - b2f(hi));
        }
    }
    __syncthreads();
    {
        f32x4 yv[4];
#pragma unroll
        for (int jt = 0; jt < 4; ++jt) yv[jt] = (f32x4){0.f, 0.f, 0.f, 0.f};
#pragma unroll
        for (int ks = 0; ks < 2; ++ks) {
            int kc = ks * 32 + quad * 8;
            short8 ah = *(const short8*)&Sh[wave * 16 + m_l][kc];
            short8 al = *(const short8*)&Sl[wave * 16 + m_l][kc];
#pragma unroll
            for (int jt = 0; jt < 4; ++jt) {
                short8 bx = *(const short8*)&Xt[jt * 16 + m_l][kc];
                yv[jt] = MFMA_B16(ah, bx, yv[jt], 0, 0, 0);
                yv[jt] = MFMA_B16(al, bx, yv[jt], 0, 0, 0);
            }
        }
#pragma unroll
        for (int jt = 0; jt < 4; ++jt)
#pragma unroll
            for (int r = 0; r < 4; ++r) {
                int i = wave * 16 + quad * 4 + r;
                int p = jt * 16 + m_l;
                y_acc[(tok0 + i) * 1024 + h * 64 + p] = f2b(yv[jt][r]);
            }
    }
    {
        f32x4 cacc = (f32x4){0.f, 0.f, 0.f, 0.f};
#pragma unroll
        for (int ks = 0; ks < 2; ++ks) {
            int kc = ks * 32 + quad * 8;
            short8 a = *(const short8*)&Bt[m_l][kc];
            short8 bh = *(const short8*)&Wh[wave * 16 + m_l][kc];
            short8 bl = *(const short8*)&Wl[wave * 16 + m_l][kc];
            cacc = MFMA_B16(a, bh, cacc, 0, 0, 0);
            cacc = MFMA_B16(a, bl, cacc, 0, 0, 0);
        }
#pragma unroll
        for (int r = 0; r < 4; ++r) {
            int n = quad * 4 + r;
            int p = wave * 16 + m_l;
            cstate[(long)bch * 1024 + n * 64 + p] = cacc[r];
        }
    }
}

// ---------------- sequential scan over chunks ----------------
__global__ __launch_bounds__(256) void scan_chunks(const float* __restrict__ cs,
                                                   const float* __restrict__ decay,
                                                   float* __restrict__ hs) {
    int t = blockIdx.x * 256 + threadIdx.x;
    int p = t & 63, n = (t >> 6) & 15, h = (t >> 10) & 15, b = t >> 14;
    float state = 0.f;
    for (int c = 0; c < 64; ++c) {
        long idx = (((long)((b * 64 + c) * 16 + h)) * 16 + n) * 64 + p;
        hs[idx] = state;
        state = decay[(b * 64 + c) * 16 + h] * state + cs[idx];
    }
}

// ---------------- y_cross + skip ----------------
__global__ __launch_bounds__(256) void ssm_cross(const u16* __restrict__ proj,
                                                 const float* __restrict__ dAcs,
                                                 const float* __restrict__ hs,
                                                 const u16* __restrict__ y_acc,
                                                 const float* __restrict__ D_param,
                                                 u16* __restrict__ y_pre) {
    int bch = blockIdx.x;
    int bc = bch >> 4, h = bch & 15;
    long tok0 = (long)bc * 64;
    __shared__ float hss[16][64], Cs[64][16], dAs[64];
    int tid = threadIdx.x;
#pragma unroll
    for (int it = 0; it < 4; ++it) {
        int li = it * 256 + tid;
        hss[li >> 6][li & 63] = hs[(long)bch * 1024 + li];
        int i = li >> 4, n = li & 15;
        Cs[i][n] = b2f(proj[(tok0 + i) * PROJ_PAD + 2304 + h * 16 + n]);
    }
    if (tid < 64) dAs[tid] = dAcs[(tok0 + tid) * 16 + h];
    __syncthreads();
    float Dh = D_param[h];
    int pi = (tid & 15) * 4;
    int ib = tid >> 4;
#pragma unroll
    for (int g = 0; g < 4; ++g) {
        int i = ib + 16 * g;
        f32x4 cr = (f32x4){0.f, 0.f, 0.f, 0.f};
#pragma unroll
        for (int n = 0; n < 16; ++n) {
            float c = Cs[i][n];
            cr += c * *(const f32x4*)&hss[n][pi];
        }
        float e = __expf(dAs[i]);
        long off = (tok0 + i) * 1024 + h * 64 + pi;
        u16x4 ya = *(const u16x4*)&y_acc[off];
        u16x4 xv = *(const u16x4*)&proj[(tok0 + i) * PROJ_PAD + h * 64 + pi];
        u16x4 o;
        o.x = f2b(b2f(ya.x) + e * cr.x + b2f(xv.x) * Dh);
        o.y = f2b(b2f(ya.y) + e * cr.y + b2f(xv.y) * Dh);
        o.z = f2b(b2f(ya.z) + e * cr.z + b2f(xv.z) * Dh);
        o.w = f2b(b2f(ya.w) + e * cr.w + b2f(xv.w) * Dh);
        *(u16x4*)&y_pre[off] = o;
    }
}

// ---------------- RMSNorm + SiLU gate (in place on y_pre) ----------------
__global__ __launch_bounds__(256) void norm_gate(const u16* __restrict__ proj,
                                                 const float* __restrict__ norm_w,
                                                 u16* __restrict__ y) {
    long tok = blockIdx.x;
    int tid = threadIdx.x;
    int c0 = tid * 4;
    u16x4 yv = *(const u16x4*)&y[tok * 1024 + c0];
    float v0 = b2f(yv.x), v1 = b2f(yv.y), v2 = b2f(yv.z), v3 = b2f(yv.w);
    float ss = v0 * v0 + v1 * v1 + v2 * v2 + v3 * v3;
    int lane = tid & 63, w = tid >> 6;
#pragma unroll
    for (int d = 32; d > 0; d >>= 1) ss += __shfl_down(ss, d, 64);
    __shared__ float red[4];
    if (lane == 0) red[w] = ss;
    __syncthreads();
    float tot = red[0] + red[1] + red[2] + red[3];
    float inv = rsqrtf(tot * (1.f / 1024.f) + 1e-6f);
    float4 nw = *(const float4*)&norm_w[c0];
    u16x4 zv = *(const u16x4*)&proj[tok * PROJ_PAD + 1024 + c0];
    float z0 = b2f(zv.x), z1 = b2f(zv.y), z2 = b2f(zv.z), z3 = b2f(zv.w);
    u16x4 o;
    o.x = f2b(v0 * inv * nw.x * (z0 / (1.f + __expf(-z0))));
    o.y = f2b(v1 * inv * nw.y * (z1 / (1.f + __expf(-z1))));
    o.z = f2b(v2 * inv * nw.z * (z2 / (1.f + __expf(-z2))));
    o.w = f2b(v3 * inv * nw.w * (z3 / (1.f + __expf(-z3))));
    *(u16x4*)&y[tok * 1024 + c0] = o;
}

extern "C" void kernel_launch(void* const* d_in, const int* in_sizes, int n_in,
                              void* d_out, int out_size, void* d_ws, size_t ws_size,
                              hipStream_t stream) {
    const float* x      = (const float*)d_in[0];
    const float* W_in   = (const float*)d_in[1];
    const float* dt_W   = (const float*)d_in[2];
    const float* dt_b   = (const float*)d_in[3];
    const float* A_log  = (const float*)d_in[4];
    const float* D_par  = (const float*)d_in[5];
    const float* W_out  = (const float*)d_in[6];
    const float* norm_w = (const float*)d_in[7];
    float* out = (float*)d_out;

    char* ws = (char*)d_ws;
    size_t off = 0;
    auto alloc = [&](size_t b) { void* p = ws + off; off += (b + 255) & ~(size_t)255; return p; };
    u16*   x_bf    = (u16*)alloc((size_t)BTOK * DK * 2);
    u16*   win_bf  = (u16*)alloc((size_t)PROJ_PAD * DK * 2);
    u16*   wout_bf = (u16*)alloc((size_t)DK * DK * 2);
    u16*   proj    = (u16*)alloc((size_t)BTOK * PROJ_PAD * 2);
    float* dAcs    = (float*)alloc((size_t)BTOK * NH * 4);
    float* decay   = (float*)alloc((size_t)NCH * NH * 4);
    float* cstate  = (float*)alloc((size_t)NCH * NH * NS * HD * 4);
    float* hstates = (float*)alloc((size_t)NCH * NH * NS * HD * 4);
    u16*   y_pre   = (u16*)alloc((size_t)BTOK * DK * 2);
    u16*   y_acc   = x_bf;  // alias: x_bf dead after GEMM1 (stream-ordered)

    static bool attr_done = false;
    if (!attr_done) {
        (void)hipFuncSetAttribute(reinterpret_cast<const void*>(&gemmk<1>),
                                  hipFuncAttributeMaxDynamicSharedMemorySize, 131072);
        (void)hipFuncSetAttribute(reinterpret_cast<const void*>(&gemmk<0>),
                                  hipFuncAttributeMaxDynamicSharedMemorySize, 131072);
        attr_done = true;
    }

    cast_bf16<<<BTOK * DK / 4 / 256, 256, 0, stream>>>(x, x_bf, BTOK * DK / 4);
    cast_bf16<<<DK * DK / 4 / 256, 256, 0, stream>>>(W_out, wout_bf, DK * DK / 4);
    cast_pad_win<<<PROJ_PAD * DK / 4 / 256, 256, 0, stream>>>(W_in, win_bf);

    // GEMM1: 16384 x 2816 x 1024 -> proj (bf16), grid 64*11 = 704 (%64==0)
    gemmk<1><<<dim3(MT * (PROJ_PAD / 256)), 512, 131072, stream>>>(x_bf, win_bf, nullptr, proj, DK, PROJ_PAD);

    ssm_intra<<<NCH * NH, 256, 0, stream>>>(proj, dt_W, dt_b, A_log, dAcs, decay, y_acc, cstate);
    scan_chunks<<<256, 256, 0, stream>>>(cstate, decay, hstates);
    ssm_cross<<<NCH * NH, 256, 0, stream>>>(proj, dAcs, hstates, y_acc, D_par, y_pre);
    norm_gate<<<BTOK, 256, 0, stream>>>(proj, norm_w, y_pre);

    // GEMM2: 16384 x 1024 x 1024 -> out (fp32), grid 64*4 = 256 (%64==0)
    gemmk<0><<<dim3(MT * (DK / 256)), 512, 131072, stream>>>(y_pre, wout_bf, out, nullptr, DK, DK);
}